// Round 4
// baseline (838.922 us; speedup 1.0000x reference)
//
#include <hip/hip_runtime.h>
#include <hip/hip_bf16.h>
#include <math.h>

// ---------------- helpers ----------------

__device__ __forceinline__ unsigned short f2bf(float f) {
    unsigned x = __float_as_uint(f);
    unsigned r = (x + 0x7fff + ((x >> 16) & 1)) >> 16;   // round-to-nearest-even
    return (unsigned short)r;
}

__device__ __forceinline__ float bf2f(unsigned short u) {
    return __uint_as_float((unsigned)u << 16);
}

// ---------------- small utility kernels ----------------

__global__ void k_degi(const int* __restrict__ dst, int* __restrict__ cnt, int E) {
    int i = blockIdx.x * 256 + threadIdx.x;
    if (i < E) atomicAdd(&cnt[dst[i]], 1);
}

__global__ void k_dis(const int* __restrict__ cnt, float* __restrict__ dis, int n) {
    int i = blockIdx.x * 256 + threadIdx.x;
    if (i < n) dis[i] = rsqrtf((float)cnt[i] + 1.0f);
}

__global__ void k_cntg(const int* __restrict__ batch, float* __restrict__ cntg, int n) {
    int i = blockIdx.x * 256 + threadIdx.x;
    if (i < n) atomicAdd(&cntg[batch[i]], 1.0f);
}

// single-block exclusive scan of cnt[0..n) -> rowptr[0..n], rowptr[n]=total
__global__ __launch_bounds__(1024) void k_scan(const int* __restrict__ cnt,
                                               int* __restrict__ rowptr, int n) {
    __shared__ int sm[1024];
    __shared__ int carry;
    const int tid = threadIdx.x;
    if (tid == 0) carry = 0;
    __syncthreads();
    for (int base = 0; base < n; base += 1024) {
        int i = base + tid;
        int v = (i < n) ? cnt[i] : 0;
        sm[tid] = v;
        __syncthreads();
#pragma unroll
        for (int o = 1; o < 1024; o <<= 1) {
            int t = (tid >= o) ? sm[tid - o] : 0;
            __syncthreads();
            sm[tid] += t;
            __syncthreads();
        }
        if (i < n) rowptr[i] = carry + sm[tid] - v;
        __syncthreads();
        if (tid == 0) carry += sm[1023];
        __syncthreads();
    }
    if (tid == 0) rowptr[n] = carry;
}

__global__ void k_fillcsr(const int* __restrict__ src, const int* __restrict__ dst,
                          const float* __restrict__ dis, const int* __restrict__ rowptr,
                          int* __restrict__ fill, int* __restrict__ csrc,
                          float* __restrict__ cw, int E) {
    int e = blockIdx.x * 256 + threadIdx.x;
    if (e >= E) return;
    int d = dst[e], s = src[e];
    int p = rowptr[d] + atomicAdd(&fill[d], 1);
    csrc[p] = s;
    cw[p] = dis[s] * dis[d];
}

// ---------------- fp32 GEMM, bf16 output: C[M,256] = A[M,256] @ B[256,256] ----------------

__global__ __launch_bounds__(256) void k_gemm256(const float* __restrict__ A,
                                                 const float* __restrict__ B,
                                                 unsigned short* __restrict__ C, int M) {
    __shared__ float As[16][68];
    __shared__ float Bs[16][68];
    const int bm = blockIdx.x;
    const int bn = blockIdx.y;          // 0..3
    const int t  = threadIdx.x;
    const int ty = t >> 4, tx = t & 15;
    const int row0 = bm * 64;

    const int ar = t >> 2;
    const int ac = (t & 3) * 4;
    const int br = t >> 4;
    const int bc = (t & 15) * 4;

    float acc[4][4] = {};

    for (int k0 = 0; k0 < 256; k0 += 16) {
        float4 av = make_float4(0.f, 0.f, 0.f, 0.f);
        int arow = row0 + ar;
        if (arow < M) av = *(const float4*)(A + (size_t)arow * 256 + k0 + ac);
        As[ac + 0][ar] = av.x;
        As[ac + 1][ar] = av.y;
        As[ac + 2][ar] = av.z;
        As[ac + 3][ar] = av.w;

        float4 bv = *(const float4*)(B + (size_t)(k0 + br) * 256 + bn * 64 + bc);
        *(float4*)(&Bs[br][bc]) = bv;

        __syncthreads();
#pragma unroll
        for (int k = 0; k < 16; ++k) {
            float a[4], b[4];
#pragma unroll
            for (int i = 0; i < 4; ++i) a[i] = As[k][ty * 4 + i];
#pragma unroll
            for (int j = 0; j < 4; ++j) b[j] = Bs[k][tx * 4 + j];
#pragma unroll
            for (int i = 0; i < 4; ++i)
#pragma unroll
                for (int j = 0; j < 4; ++j) acc[i][j] += a[i] * b[j];
        }
        __syncthreads();
    }

#pragma unroll
    for (int i = 0; i < 4; ++i) {
        int r = row0 + ty * 4 + i;
        if (r < M) {
            ushort4 o;
            o.x = f2bf(acc[i][0]);
            o.y = f2bf(acc[i][1]);
            o.z = f2bf(acc[i][2]);
            o.w = f2bf(acc[i][3]);
            *(ushort4*)(C + (size_t)r * 256 + bn * 64 + tx * 4) = o;
        }
    }
}

// ---------------- feature-tiled CSR gather ----------------
// blockIdx.y = tile (8 tiles x 32 features, bf16 slice = 3.2 MB -> fits per-XCD L2).
// One wave per dst row; lanes = (4 edge-slots es) x (16 feature-lanes fl),
// each lane covers 2 features (one uint of 2 bf16). One vector-load instruction
// fetches 4 source-row slices at once; shfl_xor(16/32) folds edge-slots.

#define TILE_F 32

// layer-0: gather + bias + relu -> partial attention dots (atomic into t, dvec)
__global__ __launch_bounds__(256) void k_gather0_t(const unsigned short* __restrict__ H,
                                                   const float* __restrict__ dis,
                                                   const int* __restrict__ rowptr,
                                                   const int* __restrict__ csrc,
                                                   const float* __restrict__ cw,
                                                   const float* __restrict__ b0,
                                                   const float* __restrict__ attnW,
                                                   const float* __restrict__ hw,
                                                   float* __restrict__ t,
                                                   float* __restrict__ dvec, int n) {
    const int row = blockIdx.x * 4 + (threadIdx.x >> 6);
    if (row >= n) return;
    const int lane = threadIdx.x & 63;
    const int es = lane >> 4;            // edge slot 0..3
    const int fl = lane & 15;            // feature-pair lane
    const int col = blockIdx.y * TILE_F + fl * 2;

    float a0 = 0.f, a1 = 0.f;
    if (es == 0) {
        float di = dis[row];
        float sn = di * di;
        unsigned u = *(const unsigned*)(H + (size_t)row * 256 + col);
        a0 = bf2f((unsigned short)(u & 0xffff)) * sn;
        a1 = bf2f((unsigned short)(u >> 16)) * sn;
    }
    int e  = rowptr[row];
    const int e1 = rowptr[row + 1];
    for (; e + 8 <= e1; e += 8) {
        int eA = e + es, eB = e + 4 + es;
        int sA = csrc[eA], sB = csrc[eB];
        float wA = cw[eA], wB = cw[eB];
        unsigned uA = *(const unsigned*)(H + (size_t)sA * 256 + col);
        unsigned uB = *(const unsigned*)(H + (size_t)sB * 256 + col);
        a0 += bf2f((unsigned short)(uA & 0xffff)) * wA;
        a1 += bf2f((unsigned short)(uA >> 16)) * wA;
        a0 += bf2f((unsigned short)(uB & 0xffff)) * wB;
        a1 += bf2f((unsigned short)(uB >> 16)) * wB;
    }
    for (; e + 4 <= e1; e += 4) {
        int ee = e + es;
        int s = csrc[ee];
        float w = cw[ee];
        unsigned u = *(const unsigned*)(H + (size_t)s * 256 + col);
        a0 += bf2f((unsigned short)(u & 0xffff)) * w;
        a1 += bf2f((unsigned short)(u >> 16)) * w;
    }
    {
        int ee = e + es;
        if (ee < e1) {
            int s = csrc[ee];
            float w = cw[ee];
            unsigned u = *(const unsigned*)(H + (size_t)s * 256 + col);
            a0 += bf2f((unsigned short)(u & 0xffff)) * w;
            a1 += bf2f((unsigned short)(u >> 16)) * w;
        }
    }
    // fold edge slots (all lanes end with the full sum for their feature pair)
    a0 += __shfl_xor(a0, 16); a0 += __shfl_xor(a0, 32);
    a1 += __shfl_xor(a1, 16); a1 += __shfl_xor(a1, 32);

    float2 bb = *(const float2*)(b0 + col);
    float v0 = fmaxf(a0 + bb.x, 0.f);
    float v1 = fmaxf(a1 + bb.y, 0.f);
    float2 aw = *(const float2*)(attnW + col);
    float2 hv = *(const float2*)(hw + col);
    float tp = v0 * aw.x + v1 * aw.y;
    float dp = v0 * hv.x + v1 * hv.y;
#pragma unroll
    for (int o = 32; o >= 1; o >>= 1) {
        tp += __shfl_down(tp, o);
        dp += __shfl_down(dp, o);
    }
    if (lane == 0) {
        atomicAdd(&t[row],    tp * 0.25f);   // wave-sum counted each es slot 4x
        atomicAdd(&dvec[row], dp * 0.25f);
    }
}

// layer-2: gather + bias + relu -> mean-pool accumulate (atomic into pooled slice)
__global__ __launch_bounds__(256) void k_gather_pool_t(const unsigned short* __restrict__ H,
                                                       const float* __restrict__ dis,
                                                       const int* __restrict__ rowptr,
                                                       const int* __restrict__ csrc,
                                                       const float* __restrict__ cw,
                                                       const float* __restrict__ b2,
                                                       const int* __restrict__ batch,
                                                       float* __restrict__ pooled, int n) {
    const int row = blockIdx.x * 4 + (threadIdx.x >> 6);
    if (row >= n) return;
    const int lane = threadIdx.x & 63;
    const int es = lane >> 4;
    const int fl = lane & 15;
    const int col = blockIdx.y * TILE_F + fl * 2;

    float a0 = 0.f, a1 = 0.f;
    if (es == 0) {
        float di = dis[row];
        float sn = di * di;
        unsigned u = *(const unsigned*)(H + (size_t)row * 256 + col);
        a0 = bf2f((unsigned short)(u & 0xffff)) * sn;
        a1 = bf2f((unsigned short)(u >> 16)) * sn;
    }
    int e  = rowptr[row];
    const int e1 = rowptr[row + 1];
    for (; e + 8 <= e1; e += 8) {
        int eA = e + es, eB = e + 4 + es;
        int sA = csrc[eA], sB = csrc[eB];
        float wA = cw[eA], wB = cw[eB];
        unsigned uA = *(const unsigned*)(H + (size_t)sA * 256 + col);
        unsigned uB = *(const unsigned*)(H + (size_t)sB * 256 + col);
        a0 += bf2f((unsigned short)(uA & 0xffff)) * wA;
        a1 += bf2f((unsigned short)(uA >> 16)) * wA;
        a0 += bf2f((unsigned short)(uB & 0xffff)) * wB;
        a1 += bf2f((unsigned short)(uB >> 16)) * wB;
    }
    for (; e + 4 <= e1; e += 4) {
        int ee = e + es;
        int s = csrc[ee];
        float w = cw[ee];
        unsigned u = *(const unsigned*)(H + (size_t)s * 256 + col);
        a0 += bf2f((unsigned short)(u & 0xffff)) * w;
        a1 += bf2f((unsigned short)(u >> 16)) * w;
    }
    {
        int ee = e + es;
        if (ee < e1) {
            int s = csrc[ee];
            float w = cw[ee];
            unsigned u = *(const unsigned*)(H + (size_t)s * 256 + col);
            a0 += bf2f((unsigned short)(u & 0xffff)) * w;
            a1 += bf2f((unsigned short)(u >> 16)) * w;
        }
    }
    a0 += __shfl_xor(a0, 16); a0 += __shfl_xor(a0, 32);
    a1 += __shfl_xor(a1, 16); a1 += __shfl_xor(a1, 32);

    if (es == 0) {
        float2 bb = *(const float2*)(b2 + col);
        float v0 = fmaxf(a0 + bb.x, 0.f);
        float v1 = fmaxf(a1 + bb.y, 0.f);
        int g = batch[row];
        float* pg = pooled + (size_t)g * 256 + col;
        atomicAdd(pg + 0, v0);
        atomicAdd(pg + 1, v1);
    }
}

// ---------------- global softmax over N ----------------

__global__ __launch_bounds__(256) void k_max1(const float* __restrict__ t,
                                              float* __restrict__ partial, int n) {
    __shared__ float sm[256];
    float m = -INFINITY;
    for (int i = blockIdx.x * 256 + threadIdx.x; i < n; i += 256 * 256)
        m = fmaxf(m, t[i]);
    sm[threadIdx.x] = m;
    __syncthreads();
    for (int s = 128; s > 0; s >>= 1) {
        if (threadIdx.x < s) sm[threadIdx.x] = fmaxf(sm[threadIdx.x], sm[threadIdx.x + s]);
        __syncthreads();
    }
    if (threadIdx.x == 0) partial[blockIdx.x] = sm[0];
}

__global__ __launch_bounds__(256) void k_max2(const float* __restrict__ partial,
                                              float* __restrict__ M) {
    __shared__ float sm[256];
    sm[threadIdx.x] = partial[threadIdx.x];
    __syncthreads();
    for (int s = 128; s > 0; s >>= 1) {
        if (threadIdx.x < s) sm[threadIdx.x] = fmaxf(sm[threadIdx.x], sm[threadIdx.x + s]);
        __syncthreads();
    }
    if (threadIdx.x == 0) *M = sm[0];
}

__global__ __launch_bounds__(256) void k_sum1(const float* __restrict__ t,
                                              const float* __restrict__ M,
                                              float* __restrict__ partial, int n) {
    __shared__ float sm[256];
    float m = *M;
    float s0 = 0.f;
    for (int i = blockIdx.x * 256 + threadIdx.x; i < n; i += 256 * 256)
        s0 += expf(t[i] - m);
    sm[threadIdx.x] = s0;
    __syncthreads();
    for (int s = 128; s > 0; s >>= 1) {
        if (threadIdx.x < s) sm[threadIdx.x] += sm[threadIdx.x + s];
        __syncthreads();
    }
    if (threadIdx.x == 0) partial[blockIdx.x] = sm[0];
}

__global__ __launch_bounds__(256) void k_sum2(const float* __restrict__ partial,
                                              float* __restrict__ S) {
    __shared__ float sm[256];
    sm[threadIdx.x] = partial[threadIdx.x];
    __syncthreads();
    for (int s = 128; s > 0; s >>= 1) {
        if (threadIdx.x < s) sm[threadIdx.x] += sm[threadIdx.x + s];
        __syncthreads();
    }
    if (threadIdx.x == 0) *S = sm[0];
}

__global__ void k_z(const float* __restrict__ t, const float* __restrict__ dvec,
                    const float* __restrict__ M, const float* __restrict__ S,
                    float* __restrict__ z, int n) {
    int i = blockIdx.x * 256 + threadIdx.x;
    if (i >= n) return;
    z[i] = expf(t[i] - *M) / *S * dvec[i];
}

// scalar CSR gather: zagg_i = z_i/deg_i + sum_e z[src]*w
__global__ void k_zgather(const float* __restrict__ z, const float* __restrict__ dis,
                          const int* __restrict__ rowptr, const int* __restrict__ csrc,
                          const float* __restrict__ cw, float* __restrict__ zagg, int n) {
    int i = blockIdx.x * 256 + threadIdx.x;
    if (i >= n) return;
    float di = dis[i];
    float a = z[i] * di * di;
    int e1 = rowptr[i + 1];
    for (int e = rowptr[i]; e < e1; ++e) a += z[csrc[e]] * cw[e];
    zagg[i] = a;
}

// h1[i,j] = relu(zagg[i]*W1[j] + b1[j])  (fp32 out, feeds GEMM2)
__global__ void k_h1(const float* __restrict__ zagg, const float* __restrict__ W1,
                     const float* __restrict__ b1, float* __restrict__ H1, int n) {
    int idx = blockIdx.x * 256 + threadIdx.x;
    int total = n * 64;
    if (idx >= total) return;
    int row = idx >> 6, lane = idx & 63;
    float s = zagg[row];
    float4 w  = ((const float4*)W1)[lane];
    float4 bb = ((const float4*)b1)[lane];
    float4 v;
    v.x = fmaxf(s * w.x + bb.x, 0.f);
    v.y = fmaxf(s * w.y + bb.y, 0.f);
    v.z = fmaxf(s * w.z + bb.z, 0.f);
    v.w = fmaxf(s * w.w + bb.w, 0.f);
    ((float4*)H1)[idx] = v;
}

// per-graph head
__global__ __launch_bounds__(64) void k_final(const float* __restrict__ pooled,
                                              const float* __restrict__ cntg,
                                              const float* __restrict__ Wout,
                                              const float* __restrict__ bout,
                                              float* __restrict__ out, int ngraphs) {
    int g = blockIdx.x;
    if (g >= ngraphs) return;
    int lane = threadIdx.x;
    float inv = 1.0f / fmaxf(cntg[g], 1.0f);
    float4 p = ((const float4*)(pooled + (size_t)g * 256))[lane];
    p.x *= inv; p.y *= inv; p.z *= inv; p.w *= inv;
    __shared__ float logits[16];
    for (int j = 0; j < 16; ++j) {
        int k = lane * 4;
        float s = p.x * Wout[(k + 0) * 16 + j] + p.y * Wout[(k + 1) * 16 + j] +
                  p.z * Wout[(k + 2) * 16 + j] + p.w * Wout[(k + 3) * 16 + j];
#pragma unroll
        for (int o = 32; o >= 1; o >>= 1) s += __shfl_down(s, o);
        if (lane == 0) logits[j] = s + bout[j];
    }
    __syncthreads();
    if (lane == 0) {
        float m = -INFINITY;
        for (int j = 0; j < 16; ++j) m = fmaxf(m, logits[j]);
        float S = 0.f;
        for (int j = 0; j < 16; ++j) S += expf(logits[j] - m);
        float lse = m + logf(S);
        for (int j = 0; j < 16; ++j) out[g * 16 + j] = logits[j] - lse;
    }
}

// ---------------- launch ----------------

extern "C" void kernel_launch(void* const* d_in, const int* in_sizes, int n_in,
                              void* d_out, int out_size, void* d_ws, size_t ws_size,
                              hipStream_t stream) {
    const float* x     = (const float*)d_in[0];
    const int*   eidx  = (const int*)d_in[1];
    const int*   batch = (const int*)d_in[2];
    const float* W0    = (const float*)d_in[3];
    const float* b0    = (const float*)d_in[4];
    const float* attnW = (const float*)d_in[5];
    const float* hw    = (const float*)d_in[7];
    const float* W1    = (const float*)d_in[8];
    const float* b1    = (const float*)d_in[9];
    const float* W2    = (const float*)d_in[10];
    const float* b2    = (const float*)d_in[11];
    const float* Wout  = (const float*)d_in[12];
    const float* bout  = (const float*)d_in[13];
    float* out = (float*)d_out;

    const int N  = in_sizes[0] / 256;
    const int E  = in_sizes[1] / 2;
    const int NG = 512;

    const int* src = eidx;
    const int* dst = eidx + E;

    // workspace layout (4-byte elements, each region 16B-aligned)
    float* wsf = (float*)d_ws;
    size_t off = 0;
    auto alloc = [&](size_t n) { size_t o = off; off = (off + n + 15) & ~(size_t)15; return o; };
    float*          bufA   = wsf + alloc((size_t)N * 256);   // h1 (fp32)
    unsigned short* bufHb  = (unsigned short*)(wsf + alloc((size_t)N * 128)); // hpre0/hpre2 bf16
    float* dis    = wsf + alloc(N);
    float* zbuf   = wsf + alloc(N);
    float* zagg   = wsf + alloc(N);
    int*   rowptr = (int*)(wsf + alloc(N + 1));
    int*   csrc   = (int*)(wsf + alloc(E));
    float* cw     = wsf + alloc(E);
    float* part1  = wsf + alloc(256);
    float* part2  = wsf + alloc(256);
    float* Msc    = wsf + alloc(16);
    float* Ssc    = wsf + alloc(16);
    // zero region: tbuf[N], dvec[N], cnti[N], fill[N], pooled[NG*256], cntg[NG]
    size_t zoff   = off;
    float* tbuf   = wsf + alloc(N);
    float* dvec   = wsf + alloc(N);
    int*   cnti   = (int*)(wsf + alloc(N));
    int*   fill   = (int*)(wsf + alloc(N));
    float* pooled = wsf + alloc((size_t)NG * 256);
    float* cntg   = wsf + alloc(NG);
    size_t zbytes = (off - zoff) * sizeof(float);

    const int TB = 256;
    dim3 blk(TB);

    hipMemsetAsync(wsf + zoff, 0, zbytes, stream);

    // CSR build
    k_degi<<<dim3((E + TB - 1) / TB), blk, 0, stream>>>(dst, cnti, E);
    k_scan<<<dim3(1), dim3(1024), 0, stream>>>(cnti, rowptr, N);
    k_dis<<<dim3((N + TB - 1) / TB), blk, 0, stream>>>(cnti, dis, N);
    k_fillcsr<<<dim3((E + TB - 1) / TB), blk, 0, stream>>>(src, dst, dis, rowptr, fill, csrc, cw, E);
    k_cntg<<<dim3((N + TB - 1) / TB), blk, 0, stream>>>(batch, cntg, N);

    // layer 0
    k_gemm256<<<dim3((N + 63) / 64, 4), blk, 0, stream>>>(x, W0, bufHb, N);
    k_gather0_t<<<dim3((N + 3) / 4, 8), blk, 0, stream>>>(bufHb, dis, rowptr, csrc, cw,
                                                          b0, attnW, hw, tbuf, dvec, N);
    // softmax over N  (attn_b dropped: softmax is shift-invariant)
    k_max1<<<dim3(256), blk, 0, stream>>>(tbuf, part1, N);
    k_max2<<<dim3(1), blk, 0, stream>>>(part1, Msc);
    k_sum1<<<dim3(256), blk, 0, stream>>>(tbuf, Msc, part2, N);
    k_sum2<<<dim3(1), blk, 0, stream>>>(part2, Ssc);
    k_z<<<dim3((N + TB - 1) / TB), blk, 0, stream>>>(tbuf, dvec, Msc, Ssc, zbuf, N);

    // layer 1 (rank-1): scalar CSR gather then broadcast
    k_zgather<<<dim3((N + TB - 1) / TB), blk, 0, stream>>>(zbuf, dis, rowptr, csrc, cw, zagg, N);
    k_h1<<<dim3((N * 64 + TB - 1) / TB), blk, 0, stream>>>(zagg, W1, b1, bufA, N);

    // layer 2
    k_gemm256<<<dim3((N + 63) / 64, 4), blk, 0, stream>>>(bufA, W2, bufHb, N);
    k_gather_pool_t<<<dim3((N + 3) / 4, 8), blk, 0, stream>>>(bufHb, dis, rowptr, csrc, cw,
                                                              b2, batch, pooled, N);
    k_final<<<dim3(NG), dim3(64), 0, stream>>>(pooled, cntg, Wout, bout, out, NG);
}